// Round 2
// baseline (296.568 us; speedup 1.0000x reference)
//
#include <hip/hip_runtime.h>

typedef unsigned short u16;
typedef __attribute__((ext_vector_type(8))) short bf16x8;   // 8 bf16 (4 VGPRs)
typedef __attribute__((ext_vector_type(4))) float f32x4;    // 4 f32 accum

#define NS 512   // subsequences per channel
#define NL 256   // d_model
#define NBD 64   // B*D channels
#define OUT_ELEMS 8388608u          // 8*4096*256 (first output, f32)
// block output: base OUT_ELEMS, per-batch stride 4096*4096 = 1<<24 (f32)

__device__ __forceinline__ u16 f2bf(float f) {
  union { float f; unsigned u; } v; v.f = f;
  unsigned u = v.u;
  unsigned r = (u + 0x7FFFu + ((u >> 16) & 1u)) >> 16;   // RNE
  return (u16)r;
}

__device__ __forceinline__ bf16x8 pack8(float4 a, float4 b) {
  bf16x8 r;
  r[0] = (short)f2bf(a.x); r[1] = (short)f2bf(a.y);
  r[2] = (short)f2bf(a.z); r[3] = (short)f2bf(a.w);
  r[4] = (short)f2bf(b.x); r[5] = (short)f2bf(b.y);
  r[6] = (short)f2bf(b.z); r[7] = (short)f2bf(b.w);
  return r;
}

// ---------------- K1: QKV projection ----------------
// qkv[row][o] = x[row][:] . w[o][:] + bias[o], row in [0,32768), o in [0,768)
// q -> qws[bd][s][0:256], k -> kws[bd][s][0:256], v -> vws[bd][f][s] (transposed)
__global__ __launch_bounds__(256) void qkv_kernel(
    const float* __restrict__ x, const float* __restrict__ w,
    const float* __restrict__ bias,
    u16* __restrict__ qws, u16* __restrict__ kws, u16* __restrict__ vws)
{
  __shared__ u16 wlds[64][264];   // w-tile [out-col][k], pad 8 u16 -> 2-way (free)

  const int t = threadIdx.x;
  const int wave = t >> 6, lane = t & 63;
  const int r16 = lane & 15, kg = lane >> 4;
  const int row0 = blockIdx.x * 64;
  const int srow = row0 + wave * 16 + r16;

  // preload A fragments (x rows, f32 -> bf16) for the whole K=256
  bf16x8 a[8];
  {
    const float* xr = x + (size_t)srow * NL;
    for (int ks = 0; ks < 8; ++ks) {
      float4 f0 = *(const float4*)(xr + ks * 32 + kg * 8);
      float4 f1 = *(const float4*)(xr + ks * 32 + kg * 8 + 4);
      a[ks] = pack8(f0, f1);
    }
  }

  const int wr = t >> 2, qq = t & 3;   // staging: 64 w-rows x 4 quarters
  for (int ct = 0; ct < 12; ++ct) {
    const int col0 = ct * 64;
    __syncthreads();
    {
      const float* src = w + (size_t)(col0 + wr) * NL + qq * 64;
      u16* dst = &wlds[wr][qq * 64];
      for (int j = 0; j < 64; j += 8) {
        float4 f0 = *(const float4*)(src + j);
        float4 f1 = *(const float4*)(src + j + 4);
        *(bf16x8*)(void*)(dst + j) = pack8(f0, f1);
      }
    }
    __syncthreads();

    for (int cf = 0; cf < 4; ++cf) {
      const int cl = cf * 16 + r16;
      f32x4 acc = {0.f, 0.f, 0.f, 0.f};
      for (int ks = 0; ks < 8; ++ks) {
        bf16x8 b = *(const bf16x8*)(void*)&wlds[cl][ks * 32 + kg * 8];
        acc = __builtin_amdgcn_mfma_f32_16x16x32_bf16(a[ks], b, acc, 0, 0, 0);
      }
      const int o = col0 + cl;
      const float bv = bias[o];
      for (int i = 0; i < 4; ++i) {
        const float val = acc[i] + bv;
        const int grow = row0 + wave * 16 + kg * 4 + i;   // D: row=(lane>>4)*4+i
        const int bd = grow >> 9, s = grow & 511;
        const u16 h = f2bf(val);
        if (o < 256)      qws[((size_t)bd * NS + s) * NL + o] = h;
        else if (o < 512) kws[((size_t)bd * NS + s) * NL + (o - 256)] = h;
        else              vws[((size_t)bd * NL + (o - 512)) * NS + s] = h;
      }
    }
  }
}

// ---------------- K2: fused attention per (channel, 32-row tile) ----------------
__global__ __launch_bounds__(256) void attn_kernel(
    const u16* __restrict__ qws, const u16* __restrict__ kws,
    const u16* __restrict__ vws, float* __restrict__ out)
{
  __shared__ float Sm[32][516];   // logits -> probs (pad 4 f32)
  __shared__ float red[32][8];
  __shared__ float rowstat[32];

  const int rt = blockIdx.x, bd = blockIdx.y;   // rt fastest: same-channel locality
  const int b = bd >> 3, d = bd & 7;
  const int t = threadIdx.x, wave = t >> 6, lane = t & 63;
  const int r16 = lane & 15, kg = lane >> 4;
  const size_t ch = (size_t)bd * NS * NL;

  // Q fragments: 2 row-frags x 8 k-steps, held in regs
  bf16x8 aq[2][8];
  for (int rf = 0; rf < 2; ++rf) {
    const int s1 = rt * 32 + rf * 16 + r16;
    const u16* p = qws + ch + (size_t)s1 * NL + kg * 8;
    for (int ks = 0; ks < 8; ++ks)
      aq[rf][ks] = *(const bf16x8*)(p + ks * 32);
  }

  // QK^T / 16 -> Sm   (wave w owns key cols [w*128, w*128+128))
  for (int cf = 0; cf < 8; ++cf) {
    const int s2 = wave * 128 + cf * 16 + r16;
    const u16* p = kws + ch + (size_t)s2 * NL + kg * 8;
    f32x4 acc0 = {0, 0, 0, 0}, acc1 = {0, 0, 0, 0};
    for (int ks = 0; ks < 8; ++ks) {
      bf16x8 bfr = *(const bf16x8*)(p + ks * 32);
      acc0 = __builtin_amdgcn_mfma_f32_16x16x32_bf16(aq[0][ks], bfr, acc0, 0, 0, 0);
      acc1 = __builtin_amdgcn_mfma_f32_16x16x32_bf16(aq[1][ks], bfr, acc1, 0, 0, 0);
    }
    const int c = wave * 128 + cf * 16 + r16;
    for (int i = 0; i < 4; ++i) {
      Sm[kg * 4 + i][c]      = acc0[i] * 0.0625f;
      Sm[16 + kg * 4 + i][c] = acc1[i] * 0.0625f;
    }
  }
  __syncthreads();

  // softmax over full 512-col row (denominator INCLUDES band entries)
  const int r = t >> 3, c8 = t & 7;
  float m = -1e30f;
  for (int j = 0; j < 8; ++j)
    for (int u = 0; u < 8; ++u)
      m = fmaxf(m, Sm[r][c8 * 8 + j * 64 + u]);
  red[r][c8] = m;
  __syncthreads();
  if (t < 32) {
    float mm = red[t][0];
    for (int j = 1; j < 8; ++j) mm = fmaxf(mm, red[t][j]);
    rowstat[t] = mm;
  }
  __syncthreads();
  const float rm = rowstat[r];
  float ssum = 0.f;
  for (int j = 0; j < 8; ++j)
    for (int u = 0; u < 8; ++u) {
      const int c = c8 * 8 + j * 64 + u;
      const float e = __expf(Sm[r][c] - rm);
      Sm[r][c] = e;
      ssum += e;
    }
  red[r][c8] = ssum;
  __syncthreads();
  if (t < 32) {
    float s = 0.f;
    for (int j = 0; j < 8; ++j) s += red[t][j];
    rowstat[t] = 1.0f / s;
  }
  __syncthreads();

  // normalize + band-zero (|s1-s2|<=1) + write block-diagonal attn (f32)
  const float inv = rowstat[r];
  const int s1g = rt * 32 + r;
  float* brow = out + OUT_ELEMS + ((size_t)b << 24) +
                (size_t)(d * NS + s1g) * 4096 + d * NS;
  for (int j = 0; j < 8; ++j) {
    const int cbase = c8 * 8 + j * 64;
    float vals[8];
    for (int u = 0; u < 8; ++u) {
      const int c = cbase + u;
      float v = Sm[r][c] * inv;
      const int dd = c > s1g ? c - s1g : s1g - c;
      if (dd <= 1) v = 0.f;
      Sm[r][c] = v;
      vals[u] = v;
    }
    *(float4*)(brow + cbase)     = *(float4*)vals;
    *(float4*)(brow + cbase + 4) = *(float4*)(vals + 4);
  }
  __syncthreads();

  // O = A @ V   (wave w owns feature cols [w*64, w*64+64))
  f32x4 accO[2][4];
  for (int rf = 0; rf < 2; ++rf)
    for (int cf = 0; cf < 4; ++cf) accO[rf][cf] = (f32x4){0, 0, 0, 0};
  for (int ks = 0; ks < 16; ++ks) {
    bf16x8 pa[2];
    for (int rf = 0; rf < 2; ++rf) {
      const float* p = &Sm[rf * 16 + r16][ks * 32 + kg * 8];
      pa[rf] = pack8(*(const float4*)p, *(const float4*)(p + 4));
    }
    for (int cf = 0; cf < 4; ++cf) {
      const int f = wave * 64 + cf * 16 + r16;
      bf16x8 bv = *(const bf16x8*)(vws + ((size_t)bd * NL + f) * NS + ks * 32 + kg * 8);
      accO[0][cf] = __builtin_amdgcn_mfma_f32_16x16x32_bf16(pa[0], bv, accO[0][cf], 0, 0, 0);
      accO[1][cf] = __builtin_amdgcn_mfma_f32_16x16x32_bf16(pa[1], bv, accO[1][cf], 0, 0, 0);
    }
  }
  for (int rf = 0; rf < 2; ++rf)
    for (int cf = 0; cf < 4; ++cf) {
      const int fcol = wave * 64 + cf * 16 + r16;
      for (int i = 0; i < 4; ++i) {
        const int s1 = rt * 32 + rf * 16 + kg * 4 + i;
        out[(size_t)b * (4096u * 256u) + (size_t)(d * NS + s1) * NL + fcol] =
            accO[rf][cf][i];
      }
    }
}

extern "C" void kernel_launch(void* const* d_in, const int* in_sizes, int n_in,
                              void* d_out, int out_size, void* d_ws, size_t ws_size,
                              hipStream_t stream) {
  const float* x    = (const float*)d_in[0];   // [8,8,512,256] f32
  const float* w    = (const float*)d_in[1];   // [768,256] f32
  const float* bias = (const float*)d_in[2];   // [768] f32
  float* out = (float*)d_out;                  // f32: out(8.39M) ++ block(134.2M)

  u16* qws = (u16*)d_ws;
  u16* kws = qws + (size_t)NBD * NS * NL;
  u16* vws = kws + (size_t)NBD * NS * NL;      // 3 x 16.78 MB bf16

  // zero entire output (block output is mostly structural zeros; poison is 0xAA)
  hipMemsetAsync(d_out, 0, (size_t)out_size * sizeof(float), stream);

  qkv_kernel<<<dim3(512), 256, 0, stream>>>(x, w, bias, qws, kws, vws);
  attn_kernel<<<dim3(16, 64), 256, 0, stream>>>(qws, kws, vws, out);
}

// Round 4
// 274.042 us; speedup vs baseline: 1.0822x; 1.0822x over previous
//
#include <hip/hip_runtime.h>

typedef unsigned short u16;
typedef __attribute__((ext_vector_type(8))) short bf16x8;   // 8 bf16 (4 VGPRs)
typedef __attribute__((ext_vector_type(4))) float f32x4;    // 4 f32 (clang vec: ok for nontemporal)

#define NS 512   // subsequences per channel
#define NL 256   // d_model
#define NBD 64   // B*D channels
#define OUT_ELEMS 8388608u          // 8*4096*256 (first output, f32)
// block output: base OUT_ELEMS, per-batch stride 4096*4096 = 1<<24 (f32)

__device__ __forceinline__ u16 f2bf(float f) {
  union { float f; unsigned u; } v; v.f = f;
  unsigned u = v.u;
  unsigned r = (u + 0x7FFFu + ((u >> 16) & 1u)) >> 16;   // RNE
  return (u16)r;
}

__device__ __forceinline__ bf16x8 pack8(float4 a, float4 b) {
  bf16x8 r;
  r[0] = (short)f2bf(a.x); r[1] = (short)f2bf(a.y);
  r[2] = (short)f2bf(a.z); r[3] = (short)f2bf(a.w);
  r[4] = (short)f2bf(b.x); r[5] = (short)f2bf(b.y);
  r[6] = (short)f2bf(b.z); r[7] = (short)f2bf(b.w);
  return r;
}

__device__ __forceinline__ bf16x8 pack8v(f32x4 a, f32x4 b) {
  bf16x8 r;
  r[0] = (short)f2bf(a[0]); r[1] = (short)f2bf(a[1]);
  r[2] = (short)f2bf(a[2]); r[3] = (short)f2bf(a[3]);
  r[4] = (short)f2bf(b[0]); r[5] = (short)f2bf(b[1]);
  r[6] = (short)f2bf(b[2]); r[7] = (short)f2bf(b[3]);
  return r;
}

// ---------------- K1: QKV projection ----------------
// qkv[row][o] = x[row][:] . w[o][:] + bias[o], row in [0,32768), o in [0,768)
// q -> qws[bd][s][0:256], k -> kws[bd][s][0:256], v -> vws[bd][f][s] (transposed)
__global__ __launch_bounds__(256) void qkv_kernel(
    const float* __restrict__ x, const float* __restrict__ w,
    const float* __restrict__ bias,
    u16* __restrict__ qws, u16* __restrict__ kws, u16* __restrict__ vws)
{
  __shared__ u16 wlds[64][264];   // w-tile [out-col][k], pad 8 u16 -> 2-way (free)

  const int t = threadIdx.x;
  const int wave = t >> 6, lane = t & 63;
  const int r16 = lane & 15, kg = lane >> 4;
  const int row0 = blockIdx.x * 64;
  const int srow = row0 + wave * 16 + r16;

  // preload A fragments (x rows, f32 -> bf16) for the whole K=256
  bf16x8 a[8];
  {
    const float* xr = x + (size_t)srow * NL;
    for (int ks = 0; ks < 8; ++ks) {
      float4 f0 = *(const float4*)(xr + ks * 32 + kg * 8);
      float4 f1 = *(const float4*)(xr + ks * 32 + kg * 8 + 4);
      a[ks] = pack8(f0, f1);
    }
  }

  const int wr = t >> 2, qq = t & 3;   // staging: 64 w-rows x 4 quarters
  for (int ct = 0; ct < 12; ++ct) {
    const int col0 = ct * 64;
    __syncthreads();
    {
      const float* src = w + (size_t)(col0 + wr) * NL + qq * 64;
      u16* dst = &wlds[wr][qq * 64];
      for (int j = 0; j < 64; j += 8) {
        float4 f0 = *(const float4*)(src + j);
        float4 f1 = *(const float4*)(src + j + 4);
        *(bf16x8*)(void*)(dst + j) = pack8(f0, f1);
      }
    }
    __syncthreads();

    for (int cf = 0; cf < 4; ++cf) {
      const int cl = cf * 16 + r16;
      f32x4 acc = {0.f, 0.f, 0.f, 0.f};
      for (int ks = 0; ks < 8; ++ks) {
        bf16x8 b = *(const bf16x8*)(void*)&wlds[cl][ks * 32 + kg * 8];
        acc = __builtin_amdgcn_mfma_f32_16x16x32_bf16(a[ks], b, acc, 0, 0, 0);
      }
      const int o = col0 + cl;
      const float bv = bias[o];
      for (int i = 0; i < 4; ++i) {
        const float val = acc[i] + bv;
        const int grow = row0 + wave * 16 + kg * 4 + i;   // D: row=(lane>>4)*4+i
        const int bd = grow >> 9, s = grow & 511;
        const u16 h = f2bf(val);
        if (o < 256)      qws[((size_t)bd * NS + s) * NL + o] = h;
        else if (o < 512) kws[((size_t)bd * NS + s) * NL + (o - 256)] = h;
        else              vws[((size_t)bd * NL + (o - 512)) * NS + s] = h;
      }
    }
  }
}

// ---------------- K2: fused attention per (channel, 32-row tile) ----------------
// Writes its FULL 4096-wide block-output rows (zeros + diag data) -> no memset.
__global__ __launch_bounds__(256) void attn_kernel(
    const u16* __restrict__ qws, const u16* __restrict__ kws,
    const u16* __restrict__ vws, float* __restrict__ out)
{
  __shared__ float Sm[32][516];   // logits -> probs (pad 4 f32)
  __shared__ float red[32][8];
  __shared__ float rowstat[32];

  const int rt = blockIdx.x, bd = blockIdx.y;   // rt fastest: same-channel locality
  const int b = bd >> 3, d = bd & 7;
  const int t = threadIdx.x, wave = t >> 6, lane = t & 63;
  const int r16 = lane & 15, kg = lane >> 4;
  const size_t ch = (size_t)bd * NS * NL;

  // ---- structural zeros: off-diagonal columns of this block's 32 rows ----
  // Issued first so the streaming stores overlap QK^T / softmax compute.
  {
    const f32x4 z4 = {0.f, 0.f, 0.f, 0.f};
    float* base = out + OUT_ELEMS + ((size_t)b << 24) +
                  (size_t)(d * NS + rt * 32) * 4096;
    const int dlo = d << 7;   // data chunk: col4 in [d*128, d*128+128)
    for (int idx = t; idx < 32 * 1024; idx += 256) {
      const int row = idx >> 10, c4 = idx & 1023;
      if ((unsigned)(c4 - dlo) >= 128u)
        __builtin_nontemporal_store(z4, (f32x4*)(base + (size_t)row * 4096) + c4);
    }
  }

  // Q fragments: 2 row-frags x 8 k-steps, held in regs
  bf16x8 aq[2][8];
  for (int rf = 0; rf < 2; ++rf) {
    const int s1 = rt * 32 + rf * 16 + r16;
    const u16* p = qws + ch + (size_t)s1 * NL + kg * 8;
    for (int ks = 0; ks < 8; ++ks)
      aq[rf][ks] = *(const bf16x8*)(p + ks * 32);
  }

  // QK^T / 16 -> Sm   (wave w owns key cols [w*128, w*128+128))
  for (int cf = 0; cf < 8; ++cf) {
    const int s2 = wave * 128 + cf * 16 + r16;
    const u16* p = kws + ch + (size_t)s2 * NL + kg * 8;
    f32x4 acc0 = {0, 0, 0, 0}, acc1 = {0, 0, 0, 0};
    for (int ks = 0; ks < 8; ++ks) {
      bf16x8 bfr = *(const bf16x8*)(p + ks * 32);
      acc0 = __builtin_amdgcn_mfma_f32_16x16x32_bf16(aq[0][ks], bfr, acc0, 0, 0, 0);
      acc1 = __builtin_amdgcn_mfma_f32_16x16x32_bf16(aq[1][ks], bfr, acc1, 0, 0, 0);
    }
    const int c = wave * 128 + cf * 16 + r16;
    for (int i = 0; i < 4; ++i) {
      Sm[kg * 4 + i][c]      = acc0[i] * 0.0625f;
      Sm[16 + kg * 4 + i][c] = acc1[i] * 0.0625f;
    }
  }
  __syncthreads();

  // softmax over full 512-col row (denominator INCLUDES band entries)
  const int r = t >> 3, c8 = t & 7;
  float m = -1e30f;
  for (int j = 0; j < 8; ++j)
    for (int u = 0; u < 8; ++u)
      m = fmaxf(m, Sm[r][c8 * 8 + j * 64 + u]);
  red[r][c8] = m;
  __syncthreads();
  if (t < 32) {
    float mm = red[t][0];
    for (int j = 1; j < 8; ++j) mm = fmaxf(mm, red[t][j]);
    rowstat[t] = mm;
  }
  __syncthreads();
  const float rm = rowstat[r];
  float ssum = 0.f;
  for (int j = 0; j < 8; ++j)
    for (int u = 0; u < 8; ++u) {
      const int c = c8 * 8 + j * 64 + u;
      const float e = __expf(Sm[r][c] - rm);
      Sm[r][c] = e;
      ssum += e;
    }
  red[r][c8] = ssum;
  __syncthreads();
  if (t < 32) {
    float s = 0.f;
    for (int j = 0; j < 8; ++j) s += red[t][j];
    rowstat[t] = 1.0f / s;
  }
  __syncthreads();

  // normalize + band-zero (|s1-s2|<=1) + write block-diagonal attn (f32)
  const float inv = rowstat[r];
  const int s1g = rt * 32 + r;
  float* brow = out + OUT_ELEMS + ((size_t)b << 24) +
                (size_t)(d * NS + s1g) * 4096 + d * NS;
  for (int j = 0; j < 8; ++j) {
    const int cbase = c8 * 8 + j * 64;
    f32x4 v0, v1;
    for (int u = 0; u < 4; ++u) {
      const int c = cbase + u;
      float v = Sm[r][c] * inv;
      const int dd = c > s1g ? c - s1g : s1g - c;
      if (dd <= 1) v = 0.f;
      Sm[r][c] = v;
      v0[u] = v;
    }
    for (int u = 0; u < 4; ++u) {
      const int c = cbase + 4 + u;
      float v = Sm[r][c] * inv;
      const int dd = c > s1g ? c - s1g : s1g - c;
      if (dd <= 1) v = 0.f;
      Sm[r][c] = v;
      v1[u] = v;
    }
    __builtin_nontemporal_store(v0, (f32x4*)(brow + cbase));
    __builtin_nontemporal_store(v1, (f32x4*)(brow + cbase + 4));
  }
  __syncthreads();

  // O = A @ V   (wave w owns feature cols [w*64, w*64+64))
  f32x4 accO[2][4];
  for (int rf = 0; rf < 2; ++rf)
    for (int cf = 0; cf < 4; ++cf) accO[rf][cf] = (f32x4){0, 0, 0, 0};
  for (int ks = 0; ks < 16; ++ks) {
    bf16x8 pa[2];
    for (int rf = 0; rf < 2; ++rf) {
      const float* p = &Sm[rf * 16 + r16][ks * 32 + kg * 8];
      pa[rf] = pack8v(*(const f32x4*)p, *(const f32x4*)(p + 4));
    }
    for (int cf = 0; cf < 4; ++cf) {
      const int f = wave * 64 + cf * 16 + r16;
      bf16x8 bv = *(const bf16x8*)(vws + ((size_t)bd * NL + f) * NS + ks * 32 + kg * 8);
      accO[0][cf] = __builtin_amdgcn_mfma_f32_16x16x32_bf16(pa[0], bv, accO[0][cf], 0, 0, 0);
      accO[1][cf] = __builtin_amdgcn_mfma_f32_16x16x32_bf16(pa[1], bv, accO[1][cf], 0, 0, 0);
    }
  }
  for (int rf = 0; rf < 2; ++rf)
    for (int cf = 0; cf < 4; ++cf) {
      const int fcol = wave * 64 + cf * 16 + r16;
      for (int i = 0; i < 4; ++i) {
        const int s1 = rt * 32 + rf * 16 + kg * 4 + i;
        out[(size_t)b * (4096u * 256u) + (size_t)(d * NS + s1) * NL + fcol] =
            accO[rf][cf][i];
      }
    }
}

extern "C" void kernel_launch(void* const* d_in, const int* in_sizes, int n_in,
                              void* d_out, int out_size, void* d_ws, size_t ws_size,
                              hipStream_t stream) {
  const float* x    = (const float*)d_in[0];   // [8,8,512,256] f32
  const float* w    = (const float*)d_in[1];   // [768,256] f32
  const float* bias = (const float*)d_in[2];   // [768] f32
  float* out = (float*)d_out;                  // f32: out(8.39M) ++ block(134.2M)

  u16* qws = (u16*)d_ws;
  u16* kws = qws + (size_t)NBD * NS * NL;
  u16* vws = kws + (size_t)NBD * NS * NL;      // 3 x 16.78 MB bf16

  // No memset: attn_kernel writes every output byte (zeros + data) itself.
  qkv_kernel<<<dim3(512), 256, 0, stream>>>(x, w, bias, qws, kws, vws);
  attn_kernel<<<dim3(16, 64), 256, 0, stream>>>(qws, kws, vws, out);
}